// Round 7
// baseline (1231.547 us; speedup 1.0000x reference)
//
#include <hip/hip_runtime.h>
#include <hip/hip_cooperative_groups.h>
#include <hip/hip_bf16.h>

typedef __hip_bfloat16 bf16;
typedef __attribute__((ext_vector_type(8))) short short8;
typedef __attribute__((ext_vector_type(4))) short short4v;
typedef __attribute__((ext_vector_type(4))) float float4v;

// ---------------- workspace layout (bf16 elements) ----------------
#define EL0 16777216ull
#define E_A0 0ull
#define E_A1 (E_A0 + EL0)
#define E_A2 (E_A1 + EL0/2)
#define E_B0 (E_A2 + EL0/4)
#define E_B1 (E_B0 + EL0)
#define E_B2 (E_B1 + EL0/2)
#define E_D0 (E_B2 + EL0/4)
#define E_W1 (E_D0 + EL0)               // [3][1024][512]
#define E_W2 (E_W1 + 3ull*1024*512)
#define E_WMIX (E_W2 + 3ull*1024*512)   // [1][512][1024]
#define E_WIOU (E_WMIX + 512ull*1024)   // [3][256][512]
#define E_AFF  (E_WIOU + 3ull*256*512)
// C role lives in d_in[0] (x0); D_L1/D_L2 in d_in[1] (x1) — both dead after the
// transpose stage, restored by the harness before every launch.

__device__ __forceinline__ void gl2lds16(const bf16* g, short* l) {
    __builtin_amdgcn_global_load_lds(
        (const __attribute__((address_space(1))) unsigned int*)g,
        (__attribute__((address_space(3))) unsigned int*)l, 16, 0, 0);
}

// ---------------- param structs ----------------
struct WSeg { const float* src; bf16* dst; int Co, Ci, K, CoTot, coOff; };
struct ASeg { const float* g; const float* be; const float* m; const float* v;
              const float* cb; float* out; int C, S; };
struct MegaP {
    WSeg wseg[6];
    ASeg aseg[6];
    const float* tx[3]; bf16* ty[3];
    const bf16* c1xa[3]; const bf16* c1xb[3]; const bf16* c1xc[3]; bf16* c1ya[3]; bf16* c1yb[3];
    const bf16* c2xa[3]; const bf16* c2xb[3]; const bf16* c2xc[3]; bf16* c2ya[3]; bf16* c2yb[3];
    const bf16* mxa[3];  const bf16* mxb[3];  const bf16* mxc[3];  bf16* mya[3];  bf16* myb[3];
    const bf16* ixa[3];  const bf16* ixb[3];  const bf16* ixc[3];  bf16* iya[3];  bf16* iyb[3];
    const bf16 *W1, *W2, *WMIX, *WIOU;
    const float* AFF;
    const bf16* hL[3]; float* oL[3];
    const bf16* hP[3]; float* oP[3];
    const bf16* hI[3]; float* oI[3];
    const float *logits_w, *logits_b, *pred_w, *pred_b, *scales, *iou_w2, *iou_b2;
    float* locs;
};

// ---------------- conv tile ----------------
__device__ __forceinline__ void conv_tile(
    int bx, int gy, int b,
    const bf16* const* Xav, const bf16* const* Xbv, int xbsel,
    const bf16* const* Xcv, int xsplit, int Cin,
    const bf16* __restrict__ Wt, int taps, int CoutTot,
    const float* __restrict__ aff,
    bf16* const* Yav, bf16* const* Ybv, int ybsel, int ystride,
    short* Alds, short* Wlds)
{
    int lvl = (gy >= 12) ? 2 : (gy >= 8) ? 1 : 0;
    int tb  = (lvl == 2) ? 12 : (lvl == 1) ? 8 : 0;
    int T = 1024 >> lvl;
    int t0 = (gy - tb) * 128;

    int co0 = bx * 128;
    int tid = threadIdx.x;
    int lane = tid & 63, wv = tid >> 6;
    int wm = wv >> 1, wn = wv & 1;
    int quad = lane >> 4, l15 = lane & 15;
    int lr = lane >> 2, lp = lane & 3;

    const bf16* X0 = (bx < xbsel) ? Xav[lvl] : Xbv[lvl];
    const bf16* Xc = Xcv[lvl];

    float4v acc[4][4] = {};

    int kIters = Cin >> 5;
    int row0 = (taps == 3) ? 1 : 0;
    int pg = (lp - (lr >> 1)) & 3;
    int wslot = ((quad + (l15 >> 1)) & 3) * 8;

    for (int kk = 0; kk < kIters; kk++) {
        int ci0 = kk << 5;
        const bf16* Xk; int cl;
        if (ci0 < xsplit) { Xk = X0; cl = ci0; } else { Xk = Xc; cl = ci0 - xsplit; }
        __syncthreads();   // also guards LDS reuse across consecutive tiles

        for (int inst = wv; inst < 8; inst += 4) {
            int row = inst * 16 + lr;
            const bf16* g = Xk + ((size_t)b * T + t0 + row) * 512 + cl + pg * 8;
            gl2lds16(g, &Alds[(row0 + inst * 16) * 32]);
        }
        for (int inst = wv; inst < taps * 8; inst += 4) {
            int tap = inst >> 3, i2 = inst & 7;
            int row = i2 * 16 + lr;
            const bf16* g = Wt + ((size_t)tap * CoutTot + co0 + row) * Cin + ci0 + pg * 8;
            gl2lds16(g, &Wlds[tap * 4096 + i2 * 512]);
        }
        if (taps == 3 && tid < 8) {
            int top = tid >> 2;
            int h = top ? 129 : 0;
            int tg = top ? t0 + 128 : t0 - 1;
            int part = tid & 3;
            int slot = top ? part : ((part + 3) & 3);
            short8 v = {0, 0, 0, 0, 0, 0, 0, 0};
            if (tg >= 0 && tg < T)
                v = *(const short8*)(Xk + ((size_t)b * T + tg) * 512 + cl + part * 8);
            *(short8*)&Alds[h * 32 + slot * 8] = v;
        }
        __syncthreads();

        for (int tap = 0; tap < taps; tap++) {
            int aoff = ((quad + ((l15 + tap - row0) >> 1)) & 3) * 8;
            short8 af[4], bfr[4];
#pragma unroll
            for (int mi = 0; mi < 4; mi++)
                af[mi] = *(short8*)&Alds[(wm * 64 + mi * 16 + l15 + tap) * 32 + aoff];
#pragma unroll
            for (int ni = 0; ni < 4; ni++)
                bfr[ni] = *(short8*)&Wlds[tap * 4096 + (wn * 64 + ni * 16 + l15) * 32 + wslot];
#pragma unroll
            for (int mi = 0; mi < 4; mi++)
#pragma unroll
                for (int ni = 0; ni < 4; ni++)
                    acc[mi][ni] = __builtin_amdgcn_mfma_f32_16x16x32_bf16(
                        af[mi], bfr[ni], acc[mi][ni], 0, 0, 0);
        }
    }

    bf16* Yp; int colbase;
    if (bx < ybsel) { Yp = Yav[lvl]; colbase = co0; }
    else            { Yp = Ybv[lvl]; colbase = co0 - 512; }
#pragma unroll
    for (int ni = 0; ni < 4; ni++) {
        int gcol = co0 + wn * 64 + ni * 16 + l15;
        int lcol = colbase + wn * 64 + ni * 16 + l15;
        float s = aff[gcol], bb = aff[CoutTot + gcol];
#pragma unroll
        for (int mi = 0; mi < 4; mi++) {
#pragma unroll
            for (int r = 0; r < 4; r++) {
                int row = t0 + wm * 64 + mi * 16 + quad * 4 + r;
                float y = acc[mi][ni][r] * s + bb;
                y = fmaxf(y, 0.f);
                Yp[((size_t)b * T + row) * ystride + lcol] = __float2bfloat16(y);
            }
        }
    }
}

// ---------------- head unit ----------------
template<int CPL, int TAPS, int COUT, int MODE>
__device__ __forceinline__ void head_unit(
    int unit, const bf16* const* Xv, int xstride,
    const float* __restrict__ w, const float* __restrict__ bias,
    const float* __restrict__ scale_ptr, float* const* outv)
{
    constexpr int RW = 16;
    constexpr int Cin = CPL * 64;
    int lvl = (unit >= 768) ? 2 : (unit >= 512) ? 1 : 0;
    int bbase = (lvl == 2) ? 768 : (lvl == 1) ? 512 : 0;
    int T = 1024 >> lvl;
    int lane = threadIdx.x & 63, wvv = threadIdx.x >> 6;
    int r0 = (unit - bbase) * 64 + wvv * RW;
    int b = r0 / T, t0 = r0 - b * T;
    const bf16* base = Xv[lvl] + (size_t)b * T * xstride + lane * CPL;
    float* out = outv[lvl];

    float wr[COUT][TAPS][CPL];
#pragma unroll
    for (int co = 0; co < COUT; co++)
#pragma unroll
        for (int k = 0; k < TAPS; k++)
#pragma unroll
            for (int j = 0; j < CPL; j++)
                wr[co][k][j] = w[((size_t)co * Cin + lane * CPL + j) * TAPS + k];
    float bia[COUT];
#pragma unroll
    for (int co = 0; co < COUT; co++) bia[co] = bias[co];
    float sc = MODE ? scale_ptr[lvl] : 0.f;

    float fprev[CPL], fcur[CPL], fnext[CPL];
    auto loadrow = [&](int t, float* f) {
        if (t < 0 || t >= T) {
#pragma unroll
            for (int j = 0; j < CPL; j++) f[j] = 0.f;
            return;
        }
        const short* q = (const short*)(base + (size_t)t * xstride);
        if constexpr (CPL == 8) {
            short8 v = *(const short8*)q;
#pragma unroll
            for (int j = 0; j < 8; j++)
                f[j] = __uint_as_float(((unsigned)(unsigned short)v[j]) << 16);
        } else {
            short4v v = *(const short4v*)q;
#pragma unroll
            for (int j = 0; j < CPL; j++)
                f[j] = __uint_as_float(((unsigned)(unsigned short)v[j]) << 16);
        }
    };

    if constexpr (TAPS == 3) { loadrow(t0 - 1, fprev); loadrow(t0, fcur); }

    for (int i = 0; i < RW; i++) {
        int t = t0 + i;
        float acc[COUT];
#pragma unroll
        for (int co = 0; co < COUT; co++) acc[co] = 0.f;
        if constexpr (TAPS == 3) {
            loadrow(t + 1, fnext);
#pragma unroll
            for (int co = 0; co < COUT; co++)
#pragma unroll
                for (int j = 0; j < CPL; j++)
                    acc[co] += fprev[j] * wr[co][0][j] + fcur[j] * wr[co][1][j]
                             + fnext[j] * wr[co][2][j];
#pragma unroll
            for (int j = 0; j < CPL; j++) { fprev[j] = fcur[j]; fcur[j] = fnext[j]; }
        } else {
            loadrow(t, fcur);
#pragma unroll
            for (int co = 0; co < COUT; co++)
#pragma unroll
                for (int j = 0; j < CPL; j++)
                    acc[co] += fcur[j] * wr[co][0][j];
        }
#pragma unroll
        for (int co = 0; co < COUT; co++)
#pragma unroll
            for (int off = 32; off; off >>= 1)
                acc[co] += __shfl_down(acc[co], off);
        if (lane == 0) {
#pragma unroll
            for (int co = 0; co < COUT; co++) {
                float v = acc[co] + bia[co];
                if (MODE) v = expf(v * sc);
                out[((size_t)b * COUT + co) * T + t] = v;
            }
        }
    }
}

// ---------------- transpose tile ----------------
__device__ __forceinline__ void transpose_tile(int u, const float* const* xv,
                                               bf16* const* yv, float* ttile)
{
    int bx = u % 56, rest = u / 56;
    int cy = rest & 15, b = rest >> 4;
    int lvl = (bx >= 48) ? 2 : (bx >= 32) ? 1 : 0;
    int base = (lvl == 2) ? 48 : (lvl == 1) ? 32 : 0;
    int T = 1024 >> lvl;
    int t0 = (bx - base) * 32, c0 = cy * 32;
    int tx = threadIdx.x & 31, ty = threadIdx.x >> 5;
    const float* xp = xv[lvl] + ((size_t)b * 512 + c0) * T + t0;
    for (int i = 0; i < 4; i++) {
        int c = ty + i * 8;
        ttile[c * 33 + tx] = xp[(size_t)c * T + tx];
    }
    __syncthreads();
    bf16* yp = yv[lvl] + ((size_t)b * T + t0) * 512 + c0;
    for (int i = 0; i < 4; i++) {
        int t = ty + i * 8;
        yp[(size_t)t * 512 + tx] = __float2bfloat16(ttile[tx * 33 + t]);
    }
}

// ---------------- prep body (shared by mega S0 and fallback) ----------------
__device__ __forceinline__ void prep_body(const MegaP& p, unsigned bid, unsigned nb) {
    int tid = threadIdx.x;
    for (int s = 0; s < 6; s++) {
        WSeg w = p.wseg[s];
        long long n = (long long)w.Co * w.Ci * w.K;
        for (long long i = (long long)bid * 256 + tid; i < n; i += (long long)nb * 256) {
            int ci = (int)(i % w.Ci);
            long long r = i / w.Ci;
            int co = (int)(r % w.Co);
            int k  = (int)(r / w.Co);
            w.dst[((size_t)k * w.CoTot + w.coOff + co) * w.Ci + ci] =
                __float2bfloat16(w.src[((long long)co * w.Ci + ci) * w.K + k]);
        }
    }
    for (int s = 0; s < 6; s++) {
        ASeg a = p.aseg[s];
        for (int i = bid * 256 + tid; i < a.C; i += nb * 256) {
            float sc = a.g[i] * rsqrtf(a.v[i] + 1e-5f);
            a.out[i] = sc;
            a.out[a.S + i] = a.cb[i] * sc + a.be[i] - a.m[i] * sc;
        }
    }
    for (int i = bid * 256 + tid; i < 1792; i += nb * 256) {
        float v;
        if (i < 1024)      v = (float)i + 0.5f;
        else if (i < 1536) v = (float)(i - 1024) * 2.0f + 1.0f;
        else               v = (float)(i - 1536) * 4.0f + 2.0f;
        p.locs[i] = v;
    }
}

// ---------------- the mega kernel (cooperative path) ----------------
__global__ __launch_bounds__(256, 4) void mega(MegaP p) {
    __shared__ short smem[16448];           // 32896 B
    short* Alds = smem;                     // 130*32
    short* Wlds = smem + 4160;              // 3*128*32
    float* ttile = (float*)smem;            // 32*33 floats

    auto grid = cooperative_groups::this_grid();
    unsigned nb = gridDim.x, bid = blockIdx.x;
    const int BIGS = 1 << 30;

    // ---- S0: prep + input transpose ----
    prep_body(p, bid, nb);
    for (unsigned u = bid; u < 28672; u += nb) {
        transpose_tile(u, p.tx, p.ty, ttile);
        __syncthreads();
    }
    grid.sync();

    // ---- S1: tower layer 1 (cls1 || box1), 3584 tiles ----
    for (unsigned u = bid; u < 3584; u += nb) {
        int bx = u & 7, r = u >> 3, gy = r % 14, b = r / 14;
        conv_tile(bx, gy, b, p.c1xa, p.c1xb, 8, p.c1xc, BIGS, 512,
                  p.W1, 3, 1024, p.AFF + 0, p.c1ya, p.c1yb, 4, 512, Alds, Wlds);
    }
    grid.sync();

    // ---- S2: tower layer 2, 3584 tiles ----
    for (unsigned u = bid; u < 3584; u += nb) {
        int bx = u & 7, r = u >> 3, gy = r % 14, b = r / 14;
        conv_tile(bx, gy, b, p.c2xa, p.c2xb, 4, p.c2xc, BIGS, 512,
                  p.W2, 3, 1024, p.AFF + 2048, p.c2ya, p.c2yb, 4, 512, Alds, Wlds);
    }
    grid.sync();

    // ---- S3: mix (1792 tiles) + logits (896) + pred (896) ----
    for (unsigned u = bid; u < 3584; u += nb) {
        if (u < 1792) {
            int bx = u & 3, r = u >> 2, gy = r % 14, b = r / 14;
            conv_tile(bx, gy, b, p.mxa, p.mxb, 4, p.mxc, 512, 1024,
                      p.WMIX, 1, 512, p.AFF + 4096, p.mya, p.myb, 8, 512, Alds, Wlds);
        } else if (u < 2688) {
            head_unit<8, 3, 1, 0>(u - 1792, p.hL, 512, p.logits_w, p.logits_b, p.scales, p.oL);
        } else {
            head_unit<8, 3, 2, 1>(u - 2688, p.hP, 512, p.pred_w, p.pred_b, p.scales, p.oP);
        }
    }
    grid.sync();

    // ---- S4: iou tower, 896 tiles ----
    for (unsigned u = bid; u < 896; u += nb) {
        int bx = u & 1, r = u >> 1, gy = r % 14, b = r / 14;
        conv_tile(bx, gy, b, p.ixa, p.ixb, 2, p.ixc, BIGS, 512,
                  p.WIOU, 3, 256, p.AFF + 5120, p.iya, p.iyb, 2, 256, Alds, Wlds);
    }
    grid.sync();

    // ---- S5: iou head, 896 units ----
    for (unsigned u = bid; u < 896; u += nb) {
        head_unit<4, 1, 1, 0>(u, p.hI, 256, p.iou_w2, p.iou_b2, p.scales, p.oI);
    }
}

// ---------------- fallback wrappers (R5-equivalent dispatch sequence) ----------------
__global__ __launch_bounds__(256) void prep_k(MegaP p) {
    prep_body(p, blockIdx.x, gridDim.x);
}

__global__ __launch_bounds__(256) void trans_k(MegaP p) {
    __shared__ float ttile[32 * 33];
    transpose_tile(blockIdx.x, p.tx, p.ty, ttile);
}

__global__ __launch_bounds__(256, 4) void conv_k(MegaP p, int which) {
    __shared__ short smem[16448];
    short* Alds = smem;
    short* Wlds = smem + 4160;
    const int BIGS = 1 << 30;
    int bx = blockIdx.x, gy = blockIdx.y, b = blockIdx.z;
    if (which == 0)
        conv_tile(bx, gy, b, p.c1xa, p.c1xb, 8, p.c1xc, BIGS, 512,
                  p.W1, 3, 1024, p.AFF + 0, p.c1ya, p.c1yb, 4, 512, Alds, Wlds);
    else if (which == 1)
        conv_tile(bx, gy, b, p.c2xa, p.c2xb, 4, p.c2xc, BIGS, 512,
                  p.W2, 3, 1024, p.AFF + 2048, p.c2ya, p.c2yb, 4, 512, Alds, Wlds);
    else if (which == 2)
        conv_tile(bx, gy, b, p.mxa, p.mxb, 4, p.mxc, 512, 1024,
                  p.WMIX, 1, 512, p.AFF + 4096, p.mya, p.myb, 8, 512, Alds, Wlds);
    else
        conv_tile(bx, gy, b, p.ixa, p.ixb, 2, p.ixc, BIGS, 512,
                  p.WIOU, 3, 256, p.AFF + 5120, p.iya, p.iyb, 2, 256, Alds, Wlds);
}

__global__ __launch_bounds__(256) void head_k(MegaP p, int which) {
    int u = blockIdx.x;
    if (which == 0)      head_unit<8, 3, 1, 0>(u, p.hL, 512, p.logits_w, p.logits_b, p.scales, p.oL);
    else if (which == 1) head_unit<8, 3, 2, 1>(u, p.hP, 512, p.pred_w, p.pred_b, p.scales, p.oP);
    else                 head_unit<4, 1, 1, 0>(u, p.hI, 256, p.iou_w2, p.iou_b2, p.scales, p.oI);
}

// ---------------- launch ----------------
extern "C" void kernel_launch(void* const* d_in, const int* in_sizes, int n_in,
                              void* d_out, int out_size, void* d_ws, size_t ws_size,
                              hipStream_t stream) {
    const float* xin0 = (const float*)d_in[0];
    const float* xin1 = (const float*)d_in[1];
    const float* xin2 = (const float*)d_in[2];
    const float* cls_w  = (const float*)d_in[3];
    const float* cls_b  = (const float*)d_in[4];
    const float* cls_g  = (const float*)d_in[5];
    const float* cls_be = (const float*)d_in[6];
    const float* cls_m  = (const float*)d_in[7];
    const float* cls_v  = (const float*)d_in[8];
    const float* box_w  = (const float*)d_in[9];
    const float* box_b  = (const float*)d_in[10];
    const float* box_g  = (const float*)d_in[11];
    const float* box_be = (const float*)d_in[12];
    const float* box_m  = (const float*)d_in[13];
    const float* box_v  = (const float*)d_in[14];
    const float* logits_w = (const float*)d_in[15];
    const float* logits_b = (const float*)d_in[16];
    const float* pred_w   = (const float*)d_in[17];
    const float* pred_b   = (const float*)d_in[18];
    const float* scales   = (const float*)d_in[19];
    const float* mix_w  = (const float*)d_in[20];
    const float* mix_b  = (const float*)d_in[21];
    const float* mix_g  = (const float*)d_in[22];
    const float* mix_be = (const float*)d_in[23];
    const float* mix_m  = (const float*)d_in[24];
    const float* mix_v  = (const float*)d_in[25];
    const float* iou_w1 = (const float*)d_in[26];
    const float* iou_b1 = (const float*)d_in[27];
    const float* iou_g  = (const float*)d_in[28];
    const float* iou_be = (const float*)d_in[29];
    const float* iou_m  = (const float*)d_in[30];
    const float* iou_v  = (const float*)d_in[31];
    const float* iou_w2 = (const float*)d_in[32];
    const float* iou_b2 = (const float*)d_in[33];

    float* out = (float*)d_out;
    bf16* wsb = (bf16*)d_ws;

    bf16* A[3] = { wsb + E_A0, wsb + E_A1, wsb + E_A2 };
    bf16* Bb[3] = { wsb + E_B0, wsb + E_B1, wsb + E_B2 };
    bf16* C[3] = { (bf16*)xin0, (bf16*)xin0 + EL0, (bf16*)xin0 + EL0 + EL0/2 };
    bf16* D[3] = { wsb + E_D0, (bf16*)xin1, (bf16*)xin1 + EL0/2 };
    bf16* W1   = wsb + E_W1;
    bf16* W2   = wsb + E_W2;
    bf16* WMIX = wsb + E_WMIX;
    bf16* WIOU = wsb + E_WIOU;
    float* AFF = (float*)(wsb + E_AFF);

    const int WL = 512 * 512 * 3;

    MegaP p;
    p.wseg[0] = { cls_w,      W1, 512, 512, 3, 1024, 0 };
    p.wseg[1] = { box_w,      W1, 512, 512, 3, 1024, 512 };
    p.wseg[2] = { cls_w + WL, W2, 512, 512, 3, 1024, 0 };
    p.wseg[3] = { box_w + WL, W2, 512, 512, 3, 1024, 512 };
    p.wseg[4] = { mix_w,  WMIX, 512, 1024, 1, 512, 0 };
    p.wseg[5] = { iou_w1, WIOU, 256, 512, 3, 256, 0 };
    p.aseg[0] = { cls_g,       cls_be,       cls_m,       cls_v,       cls_b,       AFF + 0,          512, 1024 };
    p.aseg[1] = { box_g,       box_be,       box_m,       box_v,       box_b,       AFF + 512,        512, 1024 };
    p.aseg[2] = { cls_g + 512, cls_be + 512, cls_m + 512, cls_v + 512, cls_b + 512, AFF + 2048,       512, 1024 };
    p.aseg[3] = { box_g + 512, box_be + 512, box_m + 512, box_v + 512, box_b + 512, AFF + 2048 + 512, 512, 1024 };
    p.aseg[4] = { mix_g, mix_be, mix_m, mix_v, mix_b,  AFF + 4096, 512, 512 };
    p.aseg[5] = { iou_g, iou_be, iou_m, iou_v, iou_b1, AFF + 5120, 256, 256 };

    p.tx[0] = xin0; p.tx[1] = xin1; p.tx[2] = xin2;
    for (int l = 0; l < 3; l++) {
        p.ty[l] = A[l];
        p.c1xa[l] = A[l]; p.c1xb[l] = A[l]; p.c1xc[l] = A[l];
        p.c1ya[l] = Bb[l]; p.c1yb[l] = C[l];
        p.c2xa[l] = Bb[l]; p.c2xb[l] = C[l]; p.c2xc[l] = Bb[l];
        p.c2ya[l] = D[l]; p.c2yb[l] = A[l];
        p.mxa[l] = D[l]; p.mxb[l] = D[l]; p.mxc[l] = A[l];
        p.mya[l] = Bb[l]; p.myb[l] = Bb[l];
        p.ixa[l] = Bb[l]; p.ixb[l] = Bb[l]; p.ixc[l] = Bb[l];
        p.iya[l] = C[l]; p.iyb[l] = C[l];
        p.hL[l] = D[l]; p.hP[l] = A[l]; p.hI[l] = C[l];
    }
    p.W1 = W1; p.W2 = W2; p.WMIX = WMIX; p.WIOU = WIOU; p.AFF = AFF;
    p.oL[0] = out + 0;      p.oL[1] = out + 32768;  p.oL[2] = out + 49152;
    p.oP[0] = out + 57344;  p.oP[1] = out + 122880; p.oP[2] = out + 155648;
    p.oI[0] = out + 172032; p.oI[1] = out + 204800; p.oI[2] = out + 221184;
    p.logits_w = logits_w; p.logits_b = logits_b;
    p.pred_w = pred_w; p.pred_b = pred_b; p.scales = scales;
    p.iou_w2 = iou_w2; p.iou_b2 = iou_b2;
    p.locs = out + 229376;

    // ---- cooperative path sized by the occupancy query (host-only, capture-safe) ----
    hipError_t st = hipErrorUnknown;
    int dev = 0, nCU = 0, occ = 0;
    if (hipGetDevice(&dev) == hipSuccess &&
        hipDeviceGetAttribute(&nCU, hipDeviceAttributeMultiprocessorCount, dev) == hipSuccess &&
        hipOccupancyMaxActiveBlocksPerMultiprocessor(&occ, (const void*)mega, 256, 0) == hipSuccess &&
        occ >= 1 && nCU >= 1) {
        unsigned grid = (unsigned)occ * (unsigned)nCU;
        if (grid > 1024) grid = 1024;
        void* args[] = { &p };
        st = hipLaunchCooperativeKernel((const void*)mega, dim3(grid), dim3(256),
                                        args, 0u, stream);
    }
    if (st != hipSuccess) {
        // ---- fallback: proven R5 dispatch sequence ----
        prep_k<<<512, 256, 0, stream>>>(p);
        trans_k<<<28672, 256, 0, stream>>>(p);
        conv_k<<<dim3(8, 14, 32), 256, 0, stream>>>(p, 0);
        conv_k<<<dim3(8, 14, 32), 256, 0, stream>>>(p, 1);
        head_k<<<896, 256, 0, stream>>>(p, 0);
        head_k<<<896, 256, 0, stream>>>(p, 1);
        conv_k<<<dim3(4, 14, 32), 256, 0, stream>>>(p, 2);
        conv_k<<<dim3(2, 14, 32), 256, 0, stream>>>(p, 3);
        head_k<<<896, 256, 0, stream>>>(p, 2);
    }
}

// Round 8
// 762.611 us; speedup vs baseline: 1.6149x; 1.6149x over previous
//
#include <hip/hip_runtime.h>
#include <hip/hip_bf16.h>

typedef __hip_bfloat16 bf16;
typedef __attribute__((ext_vector_type(8))) short short8;
typedef __attribute__((ext_vector_type(4))) short short4v;
typedef __attribute__((ext_vector_type(4))) float float4v;

// ---------------- workspace layout (bf16 elements) ----------------
#define EL0 16777216ull
#define E_A0 0ull
#define E_A1 (E_A0 + EL0)
#define E_A2 (E_A1 + EL0/2)
#define E_B0 (E_A2 + EL0/4)
#define E_B1 (E_B0 + EL0)
#define E_B2 (E_B1 + EL0/2)
#define E_D0 (E_B2 + EL0/4)
#define E_W1 (E_D0 + EL0)               // [3][1024][512]
#define E_W2 (E_W1 + 3ull*1024*512)
#define E_WMIX (E_W2 + 3ull*1024*512)   // [1][512][1024]
#define E_WIOU (E_WMIX + 512ull*1024)   // [3][256][512]
#define E_AFF  (E_WIOU + 3ull*256*512)
// C role lives in d_in[0] (x0); D_L1/D_L2 in d_in[1] (x1) — both dead after the
// transpose stage, restored by the harness before every launch.

__device__ __forceinline__ void gl2lds16(const bf16* g, short* l) {
    __builtin_amdgcn_global_load_lds(
        (const __attribute__((address_space(1))) unsigned int*)g,
        (__attribute__((address_space(3))) unsigned int*)l, 16, 0, 0);
}

// ---------------- param structs ----------------
struct WSeg { const float* src; bf16* dst; int Co, Ci, K, CoTot, coOff; };
struct ASeg { const float* g; const float* be; const float* m; const float* v;
              const float* cb; float* out; int C, S; };
struct MegaP {
    WSeg wseg[6];
    ASeg aseg[6];
    const float* tx[3]; bf16* ty[3];
    const bf16* c1xa[3]; const bf16* c1xb[3]; const bf16* c1xc[3]; bf16* c1ya[3]; bf16* c1yb[3];
    const bf16* c2xa[3]; const bf16* c2xb[3]; const bf16* c2xc[3]; bf16* c2ya[3]; bf16* c2yb[3];
    const bf16* mxa[3];  const bf16* mxb[3];  const bf16* mxc[3];  bf16* mya[3];  bf16* myb[3];
    const bf16* ixa[3];  const bf16* ixb[3];  const bf16* ixc[3];  bf16* iya[3];  bf16* iyb[3];
    const bf16 *W1, *W2, *WMIX, *WIOU;
    const float* AFF;
    const bf16* hL[3]; float* oL[3];
    const bf16* hP[3]; float* oP[3];
    const bf16* hI[3]; float* oI[3];
    const float *logits_w, *logits_b, *pred_w, *pred_b, *scales, *iou_w2, *iou_b2;
    float* locs;
};

// ---------------- conv tile ----------------
__device__ __forceinline__ void conv_tile(
    int bx, int gy, int b,
    const bf16* const* Xav, const bf16* const* Xbv, int xbsel,
    const bf16* const* Xcv, int xsplit, int Cin,
    const bf16* __restrict__ Wt, int taps, int CoutTot,
    const float* __restrict__ aff,
    bf16* const* Yav, bf16* const* Ybv, int ybsel, int ystride,
    short* Alds, short* Wlds)
{
    int lvl = (gy >= 12) ? 2 : (gy >= 8) ? 1 : 0;
    int tb  = (lvl == 2) ? 12 : (lvl == 1) ? 8 : 0;
    int T = 1024 >> lvl;
    int t0 = (gy - tb) * 128;

    int co0 = bx * 128;
    int tid = threadIdx.x;
    int lane = tid & 63, wv = tid >> 6;
    int wm = wv >> 1, wn = wv & 1;
    int quad = lane >> 4, l15 = lane & 15;
    int lr = lane >> 2, lp = lane & 3;

    const bf16* X0 = (bx < xbsel) ? Xav[lvl] : Xbv[lvl];
    const bf16* Xc = Xcv[lvl];

    float4v acc[4][4] = {};

    int kIters = Cin >> 5;
    int row0 = (taps == 3) ? 1 : 0;
    int pg = (lp - (lr >> 1)) & 3;
    int wslot = ((quad + (l15 >> 1)) & 3) * 8;

    for (int kk = 0; kk < kIters; kk++) {
        int ci0 = kk << 5;
        const bf16* Xk; int cl;
        if (ci0 < xsplit) { Xk = X0; cl = ci0; } else { Xk = Xc; cl = ci0 - xsplit; }
        if (kk) __syncthreads();

        for (int inst = wv; inst < 8; inst += 4) {
            int row = inst * 16 + lr;
            const bf16* g = Xk + ((size_t)b * T + t0 + row) * 512 + cl + pg * 8;
            gl2lds16(g, &Alds[(row0 + inst * 16) * 32]);
        }
        for (int inst = wv; inst < taps * 8; inst += 4) {
            int tap = inst >> 3, i2 = inst & 7;
            int row = i2 * 16 + lr;
            const bf16* g = Wt + ((size_t)tap * CoutTot + co0 + row) * Cin + ci0 + pg * 8;
            gl2lds16(g, &Wlds[tap * 4096 + i2 * 512]);
        }
        if (taps == 3 && tid < 8) {
            int top = tid >> 2;
            int h = top ? 129 : 0;
            int tg = top ? t0 + 128 : t0 - 1;
            int part = tid & 3;
            int slot = top ? part : ((part + 3) & 3);
            short8 v = {0, 0, 0, 0, 0, 0, 0, 0};
            if (tg >= 0 && tg < T)
                v = *(const short8*)(Xk + ((size_t)b * T + tg) * 512 + cl + part * 8);
            *(short8*)&Alds[h * 32 + slot * 8] = v;
        }
        __syncthreads();

        for (int tap = 0; tap < taps; tap++) {
            int aoff = ((quad + ((l15 + tap - row0) >> 1)) & 3) * 8;
            short8 af[4], bfr[4];
#pragma unroll
            for (int mi = 0; mi < 4; mi++)
                af[mi] = *(short8*)&Alds[(wm * 64 + mi * 16 + l15 + tap) * 32 + aoff];
#pragma unroll
            for (int ni = 0; ni < 4; ni++)
                bfr[ni] = *(short8*)&Wlds[tap * 4096 + (wn * 64 + ni * 16 + l15) * 32 + wslot];
#pragma unroll
            for (int mi = 0; mi < 4; mi++)
#pragma unroll
                for (int ni = 0; ni < 4; ni++)
                    acc[mi][ni] = __builtin_amdgcn_mfma_f32_16x16x32_bf16(
                        af[mi], bfr[ni], acc[mi][ni], 0, 0, 0);
        }
    }

    bf16* Yp; int colbase;
    if (bx < ybsel) { Yp = Yav[lvl]; colbase = co0; }
    else            { Yp = Ybv[lvl]; colbase = co0 - 512; }
#pragma unroll
    for (int ni = 0; ni < 4; ni++) {
        int gcol = co0 + wn * 64 + ni * 16 + l15;
        int lcol = colbase + wn * 64 + ni * 16 + l15;
        float s = aff[gcol], bb = aff[CoutTot + gcol];
#pragma unroll
        for (int mi = 0; mi < 4; mi++) {
#pragma unroll
            for (int r = 0; r < 4; r++) {
                int row = t0 + wm * 64 + mi * 16 + quad * 4 + r;
                float y = acc[mi][ni][r] * s + bb;
                y = fmaxf(y, 0.f);
                Yp[((size_t)b * T + row) * ystride + lcol] = __float2bfloat16(y);
            }
        }
    }
}

// ---------------- head unit ----------------
template<int CPL, int TAPS, int COUT, int MODE>
__device__ __forceinline__ void head_unit(
    int unit, const bf16* const* Xv, int xstride,
    const float* __restrict__ w, const float* __restrict__ bias,
    const float* __restrict__ scale_ptr, float* const* outv)
{
    constexpr int RW = 16;
    constexpr int Cin = CPL * 64;
    int lvl = (unit >= 768) ? 2 : (unit >= 512) ? 1 : 0;
    int bbase = (lvl == 2) ? 768 : (lvl == 1) ? 512 : 0;
    int T = 1024 >> lvl;
    int lane = threadIdx.x & 63, wvv = threadIdx.x >> 6;
    int r0 = (unit - bbase) * 64 + wvv * RW;
    int b = r0 / T, t0 = r0 - b * T;
    const bf16* base = Xv[lvl] + (size_t)b * T * xstride + lane * CPL;
    float* out = outv[lvl];

    float wr[COUT][TAPS][CPL];
#pragma unroll
    for (int co = 0; co < COUT; co++)
#pragma unroll
        for (int k = 0; k < TAPS; k++)
#pragma unroll
            for (int j = 0; j < CPL; j++)
                wr[co][k][j] = w[((size_t)co * Cin + lane * CPL + j) * TAPS + k];
    float bia[COUT];
#pragma unroll
    for (int co = 0; co < COUT; co++) bia[co] = bias[co];
    float sc = MODE ? scale_ptr[lvl] : 0.f;

    float fprev[CPL], fcur[CPL], fnext[CPL];
    auto loadrow = [&](int t, float* f) {
        if (t < 0 || t >= T) {
#pragma unroll
            for (int j = 0; j < CPL; j++) f[j] = 0.f;
            return;
        }
        const short* q = (const short*)(base + (size_t)t * xstride);
        if constexpr (CPL == 8) {
            short8 v = *(const short8*)q;
#pragma unroll
            for (int j = 0; j < 8; j++)
                f[j] = __uint_as_float(((unsigned)(unsigned short)v[j]) << 16);
        } else {
            short4v v = *(const short4v*)q;
#pragma unroll
            for (int j = 0; j < CPL; j++)
                f[j] = __uint_as_float(((unsigned)(unsigned short)v[j]) << 16);
        }
    };

    if constexpr (TAPS == 3) { loadrow(t0 - 1, fprev); loadrow(t0, fcur); }

    for (int i = 0; i < RW; i++) {
        int t = t0 + i;
        float acc[COUT];
#pragma unroll
        for (int co = 0; co < COUT; co++) acc[co] = 0.f;
        if constexpr (TAPS == 3) {
            loadrow(t + 1, fnext);
#pragma unroll
            for (int co = 0; co < COUT; co++)
#pragma unroll
                for (int j = 0; j < CPL; j++)
                    acc[co] += fprev[j] * wr[co][0][j] + fcur[j] * wr[co][1][j]
                             + fnext[j] * wr[co][2][j];
#pragma unroll
            for (int j = 0; j < CPL; j++) { fprev[j] = fcur[j]; fcur[j] = fnext[j]; }
        } else {
            loadrow(t, fcur);
#pragma unroll
            for (int co = 0; co < COUT; co++)
#pragma unroll
                for (int j = 0; j < CPL; j++)
                    acc[co] += fcur[j] * wr[co][0][j];
        }
#pragma unroll
        for (int co = 0; co < COUT; co++)
#pragma unroll
            for (int off = 32; off; off >>= 1)
                acc[co] += __shfl_down(acc[co], off);
        if (lane == 0) {
#pragma unroll
            for (int co = 0; co < COUT; co++) {
                float v = acc[co] + bia[co];
                if (MODE) v = expf(v * sc);
                out[((size_t)b * COUT + co) * T + t] = v;
            }
        }
    }
}

// ---------------- transpose tile ----------------
__device__ __forceinline__ void transpose_tile(int u, const float* const* xv,
                                               bf16* const* yv, float* ttile)
{
    int bx = u % 56, rest = u / 56;
    int cy = rest & 15, b = rest >> 4;
    int lvl = (bx >= 48) ? 2 : (bx >= 32) ? 1 : 0;
    int base = (lvl == 2) ? 48 : (lvl == 1) ? 32 : 0;
    int T = 1024 >> lvl;
    int t0 = (bx - base) * 32, c0 = cy * 32;
    int tx = threadIdx.x & 31, ty = threadIdx.x >> 5;
    const float* xp = xv[lvl] + ((size_t)b * 512 + c0) * T + t0;
    for (int i = 0; i < 4; i++) {
        int c = ty + i * 8;
        ttile[c * 33 + tx] = xp[(size_t)c * T + tx];
    }
    __syncthreads();
    bf16* yp = yv[lvl] + ((size_t)b * T + t0) * 512 + c0;
    for (int i = 0; i < 4; i++) {
        int t = ty + i * 8;
        yp[(size_t)t * 512 + tx] = __float2bfloat16(ttile[tx * 33 + t]);
    }
}

// ---------------- prep body ----------------
__device__ __forceinline__ void prep_body(const MegaP& p, unsigned bid, unsigned nb) {
    int tid = threadIdx.x;
    for (int s = 0; s < 6; s++) {
        WSeg w = p.wseg[s];
        long long n = (long long)w.Co * w.Ci * w.K;
        for (long long i = (long long)bid * 256 + tid; i < n; i += (long long)nb * 256) {
            int ci = (int)(i % w.Ci);
            long long r = i / w.Ci;
            int co = (int)(r % w.Co);
            int k  = (int)(r / w.Co);
            w.dst[((size_t)k * w.CoTot + w.coOff + co) * w.Ci + ci] =
                __float2bfloat16(w.src[((long long)co * w.Ci + ci) * w.K + k]);
        }
    }
    for (int s = 0; s < 6; s++) {
        ASeg a = p.aseg[s];
        for (int i = bid * 256 + tid; i < a.C; i += nb * 256) {
            float sc = a.g[i] * rsqrtf(a.v[i] + 1e-5f);
            a.out[i] = sc;
            a.out[a.S + i] = a.cb[i] * sc + a.be[i] - a.m[i] * sc;
        }
    }
    for (int i = bid * 256 + tid; i < 1792; i += nb * 256) {
        float v;
        if (i < 1024)      v = (float)i + 0.5f;
        else if (i < 1536) v = (float)(i - 1024) * 2.0f + 1.0f;
        else               v = (float)(i - 1536) * 4.0f + 2.0f;
        p.locs[i] = v;
    }
}

// ---------------- dispatch kernels ----------------
// prep + input transpose merged (independent work): blocks [0,28672) transpose,
// [28672, 29184) prep.
__global__ __launch_bounds__(256) void prep_trans_k(MegaP p) {
    __shared__ float ttile[32 * 33];
    unsigned u = blockIdx.x;
    if (u < 28672) transpose_tile((int)u, p.tx, p.ty, ttile);
    else           prep_body(p, u - 28672, 512);
}

// which: 0=tower1, 1=tower2, 2=iou tower
__global__ __launch_bounds__(256, 4) void conv_k(MegaP p, int which) {
    __shared__ short smem[16448];
    short* Alds = smem;
    short* Wlds = smem + 4160;
    const int BIGS = 1 << 30;
    int bx = blockIdx.x, gy = blockIdx.y, b = blockIdx.z;
    if (which == 0)
        conv_tile(bx, gy, b, p.c1xa, p.c1xb, 8, p.c1xc, BIGS, 512,
                  p.W1, 3, 1024, p.AFF + 0, p.c1ya, p.c1yb, 4, 512, Alds, Wlds);
    else if (which == 1)
        conv_tile(bx, gy, b, p.c2xa, p.c2xb, 4, p.c2xc, BIGS, 512,
                  p.W2, 3, 1024, p.AFF + 2048, p.c2ya, p.c2yb, 4, 512, Alds, Wlds);
    else
        conv_tile(bx, gy, b, p.ixa, p.ixb, 2, p.ixc, BIGS, 512,
                  p.WIOU, 3, 256, p.AFF + 5120, p.iya, p.iyb, 2, 256, Alds, Wlds);
}

// mix conv (1792 blocks) + logits head (896) + pred head (896) — all depend only
// on tower2; one dispatch so the heads fill mix's scheduling tail.
__global__ __launch_bounds__(256, 4) void mixheads_k(MegaP p) {
    __shared__ short smem[16448];
    short* Alds = smem;
    short* Wlds = smem + 4160;
    unsigned u = blockIdx.x;
    if (u < 1792) {
        int bx = u & 3, r = u >> 2, gy = r % 14, b = r / 14;
        conv_tile(bx, gy, b, p.mxa, p.mxb, 4, p.mxc, 512, 1024,
                  p.WMIX, 1, 512, p.AFF + 4096, p.mya, p.myb, 8, 512, Alds, Wlds);
    } else if (u < 2688) {
        head_unit<8, 3, 1, 0>(u - 1792, p.hL, 512, p.logits_w, p.logits_b, p.scales, p.oL);
    } else {
        head_unit<8, 3, 2, 1>(u - 2688, p.hP, 512, p.pred_w, p.pred_b, p.scales, p.oP);
    }
}

__global__ __launch_bounds__(256) void iouhead_k(MegaP p) {
    head_unit<4, 1, 1, 0>(blockIdx.x, p.hI, 256, p.iou_w2, p.iou_b2, p.scales, p.oI);
}

// ---------------- launch ----------------
extern "C" void kernel_launch(void* const* d_in, const int* in_sizes, int n_in,
                              void* d_out, int out_size, void* d_ws, size_t ws_size,
                              hipStream_t stream) {
    const float* xin0 = (const float*)d_in[0];
    const float* xin1 = (const float*)d_in[1];
    const float* xin2 = (const float*)d_in[2];
    const float* cls_w  = (const float*)d_in[3];
    const float* cls_b  = (const float*)d_in[4];
    const float* cls_g  = (const float*)d_in[5];
    const float* cls_be = (const float*)d_in[6];
    const float* cls_m  = (const float*)d_in[7];
    const float* cls_v  = (const float*)d_in[8];
    const float* box_w  = (const float*)d_in[9];
    const float* box_b  = (const float*)d_in[10];
    const float* box_g  = (const float*)d_in[11];
    const float* box_be = (const float*)d_in[12];
    const float* box_m  = (const float*)d_in[13];
    const float* box_v  = (const float*)d_in[14];
    const float* logits_w = (const float*)d_in[15];
    const float* logits_b = (const float*)d_in[16];
    const float* pred_w   = (const float*)d_in[17];
    const float* pred_b   = (const float*)d_in[18];
    const float* scales   = (const float*)d_in[19];
    const float* mix_w  = (const float*)d_in[20];
    const float* mix_b  = (const float*)d_in[21];
    const float* mix_g  = (const float*)d_in[22];
    const float* mix_be = (const float*)d_in[23];
    const float* mix_m  = (const float*)d_in[24];
    const float* mix_v  = (const float*)d_in[25];
    const float* iou_w1 = (const float*)d_in[26];
    const float* iou_b1 = (const float*)d_in[27];
    const float* iou_g  = (const float*)d_in[28];
    const float* iou_be = (const float*)d_in[29];
    const float* iou_m  = (const float*)d_in[30];
    const float* iou_v  = (const float*)d_in[31];
    const float* iou_w2 = (const float*)d_in[32];
    const float* iou_b2 = (const float*)d_in[33];

    float* out = (float*)d_out;
    bf16* wsb = (bf16*)d_ws;

    bf16* A[3] = { wsb + E_A0, wsb + E_A1, wsb + E_A2 };
    bf16* Bb[3] = { wsb + E_B0, wsb + E_B1, wsb + E_B2 };
    bf16* C[3] = { (bf16*)xin0, (bf16*)xin0 + EL0, (bf16*)xin0 + EL0 + EL0/2 };
    bf16* D[3] = { wsb + E_D0, (bf16*)xin1, (bf16*)xin1 + EL0/2 };
    bf16* W1   = wsb + E_W1;
    bf16* W2   = wsb + E_W2;
    bf16* WMIX = wsb + E_WMIX;
    bf16* WIOU = wsb + E_WIOU;
    float* AFF = (float*)(wsb + E_AFF);

    const int WL = 512 * 512 * 3;

    MegaP p;
    p.wseg[0] = { cls_w,      W1, 512, 512, 3, 1024, 0 };
    p.wseg[1] = { box_w,      W1, 512, 512, 3, 1024, 512 };
    p.wseg[2] = { cls_w + WL, W2, 512, 512, 3, 1024, 0 };
    p.wseg[3] = { box_w + WL, W2, 512, 512, 3, 1024, 512 };
    p.wseg[4] = { mix_w,  WMIX, 512, 1024, 1, 512, 0 };
    p.wseg[5] = { iou_w1, WIOU, 256, 512, 3, 256, 0 };
    p.aseg[0] = { cls_g,       cls_be,       cls_m,       cls_v,       cls_b,       AFF + 0,          512, 1024 };
    p.aseg[1] = { box_g,       box_be,       box_m,       box_v,       box_b,       AFF + 512,        512, 1024 };
    p.aseg[2] = { cls_g + 512, cls_be + 512, cls_m + 512, cls_v + 512, cls_b + 512, AFF + 2048,       512, 1024 };
    p.aseg[3] = { box_g + 512, box_be + 512, box_m + 512, box_v + 512, box_b + 512, AFF + 2048 + 512, 512, 1024 };
    p.aseg[4] = { mix_g, mix_be, mix_m, mix_v, mix_b,  AFF + 4096, 512, 512 };
    p.aseg[5] = { iou_g, iou_be, iou_m, iou_v, iou_b1, AFF + 5120, 256, 256 };

    p.tx[0] = xin0; p.tx[1] = xin1; p.tx[2] = xin2;
    for (int l = 0; l < 3; l++) {
        p.ty[l] = A[l];
        p.c1xa[l] = A[l]; p.c1xb[l] = A[l]; p.c1xc[l] = A[l];
        p.c1ya[l] = Bb[l]; p.c1yb[l] = C[l];
        p.c2xa[l] = Bb[l]; p.c2xb[l] = C[l]; p.c2xc[l] = Bb[l];
        p.c2ya[l] = D[l]; p.c2yb[l] = A[l];
        p.mxa[l] = D[l]; p.mxb[l] = D[l]; p.mxc[l] = A[l];
        p.mya[l] = Bb[l]; p.myb[l] = Bb[l];
        p.ixa[l] = Bb[l]; p.ixb[l] = Bb[l]; p.ixc[l] = Bb[l];
        p.iya[l] = C[l]; p.iyb[l] = C[l];
        p.hL[l] = D[l]; p.hP[l] = A[l]; p.hI[l] = C[l];
    }
    p.W1 = W1; p.W2 = W2; p.WMIX = WMIX; p.WIOU = WIOU; p.AFF = AFF;
    p.oL[0] = out + 0;      p.oL[1] = out + 32768;  p.oL[2] = out + 49152;
    p.oP[0] = out + 57344;  p.oP[1] = out + 122880; p.oP[2] = out + 155648;
    p.oI[0] = out + 172032; p.oI[1] = out + 204800; p.oI[2] = out + 221184;
    p.logits_w = logits_w; p.logits_b = logits_b;
    p.pred_w = pred_w; p.pred_b = pred_b; p.scales = scales;
    p.iou_w2 = iou_w2; p.iou_b2 = iou_b2;
    p.locs = out + 229376;

    // 6 ordinary dispatches (cooperative persistent kernel measured 1.7x slower — R7)
    prep_trans_k<<<29184, 256, 0, stream>>>(p);
    conv_k<<<dim3(8, 14, 32), 256, 0, stream>>>(p, 0);   // tower layer1 (cls1||box1)
    conv_k<<<dim3(8, 14, 32), 256, 0, stream>>>(p, 1);   // tower layer2 (cls2||box2)
    mixheads_k<<<3584, 256, 0, stream>>>(p);             // mix + logits + pred
    conv_k<<<dim3(2, 14, 32), 256, 0, stream>>>(p, 2);   // iou tower
    iouhead_k<<<896, 256, 0, stream>>>(p);               // iou head
}